// Round 2
// baseline (307.625 us; speedup 1.0000x reference)
//
#include <hip/hip_runtime.h>
#include <hip/hip_bf16.h>

typedef short short8 __attribute__((ext_vector_type(8)));
typedef float f32x4 __attribute__((ext_vector_type(4)));
typedef int   int4v  __attribute__((ext_vector_type(4)));

#define NB   2
#define SEQ  2048
#define CH   1024
#define NH   16
#define HD   64
#define MROWS (NB*SEQ)          // 4096
#define QSZ  (NB*NH*SEQ*HD)     // 4194304 elems per tensor

__device__ __forceinline__ f32x4 mfma16(short8 a, short8 b, f32x4 c) {
    return __builtin_amdgcn_mfma_f32_16x16x32_bf16(a, b, c, 0, 0, 0);
}

__device__ __forceinline__ short bf16_of(float f) {
    return __builtin_bit_cast(short, __float2bfloat16(f));
}

// load 8 consecutive elements, yielding bf16 short8
__device__ __forceinline__ short8 load8(const __hip_bfloat16* p) {
    return *reinterpret_cast<const short8*>(p);
}
__device__ __forceinline__ short8 load8(const float* p) {
    f32x4 a = *reinterpret_cast<const f32x4*>(p);
    f32x4 b = *reinterpret_cast<const f32x4*>(p + 4);
    short8 r;
    r[0] = bf16_of(a[0]); r[1] = bf16_of(a[1]);
    r[2] = bf16_of(a[2]); r[3] = bf16_of(a[3]);
    r[4] = bf16_of(b[0]); r[5] = bf16_of(b[1]);
    r[6] = bf16_of(b[2]); r[7] = bf16_of(b[3]);
    return r;
}

// ---------------------------------------------------------------------------
// GEMM  C[m,n] = sum_k A[m,k] * W[n,k]   (A row-major [M,K], W row-major [N,K])
// 128x128 tile, BK=32, 4 waves (2x2), each wave 64x64 out = 4x4 MFMA frags.
// EPI=0: fp32 store to Cout[m*N+n]
// EPI=1: qkv routing -> q[b,h,s,d], k[b,h,s,d], vt[b,h,d,s]  (bf16 ws)
// ---------------------------------------------------------------------------
template<int EPI, typename TA, typename TW>
__global__ __launch_bounds__(256, 2)
void gemm_bt(const TA* __restrict__ A,
             const TW* __restrict__ W,
             int K, int N,
             float* __restrict__ Cout,
             __hip_bfloat16* __restrict__ qp,
             __hip_bfloat16* __restrict__ kp,
             __hip_bfloat16* __restrict__ vtp)
{
    __shared__ alignas(16) __hip_bfloat16 Asm[128 * 32];
    __shared__ alignas(16) __hip_bfloat16 Bsm[128 * 32];

    const int tid  = threadIdx.x;
    const int lane = tid & 63;
    const int wave = tid >> 6;
    const int wm   = wave >> 1, wn = wave & 1;
    const int l15  = lane & 15, lg = lane >> 4;
    const int m0   = blockIdx.x * 128;
    const int n0   = blockIdx.y * 128;

    f32x4 acc[4][4] = {};

    // staging chunk mapping: 512 8-elem chunks per tile, 2 per thread
    const int c0 = tid, c1 = tid + 256;
    const int r0 = c0 >> 2, kc0 = (c0 & 3) << 3;
    const int r1 = c1 >> 2, kc1 = (c1 & 3) << 3;
    const TA* a0p = A + (size_t)(m0 + r0) * K + kc0;
    const TA* a1p = A + (size_t)(m0 + r1) * K + kc1;
    const TW* b0p = W + (size_t)(n0 + r0) * K + kc0;
    const TW* b1p = W + (size_t)(n0 + r1) * K + kc1;

    for (int k0 = 0; k0 < K; k0 += 32) {
        short8 av0 = load8(a0p + k0);
        short8 av1 = load8(a1p + k0);
        short8 bv0 = load8(b0p + k0);
        short8 bv1 = load8(b1p + k0);
        __syncthreads();   // previous iteration's LDS reads done
        *(short8*)&Asm[c0 * 8] = av0;
        *(short8*)&Asm[c1 * 8] = av1;
        *(short8*)&Bsm[c0 * 8] = bv0;
        *(short8*)&Bsm[c1 * 8] = bv1;
        __syncthreads();

        short8 af[4], bfr[4];
        #pragma unroll
        for (int mi = 0; mi < 4; ++mi)
            af[mi] = *(const short8*)&Asm[(wm * 64 + mi * 16 + l15) * 32 + lg * 8];
        #pragma unroll
        for (int ni = 0; ni < 4; ++ni)
            bfr[ni] = *(const short8*)&Bsm[(wn * 64 + ni * 16 + l15) * 32 + lg * 8];
        #pragma unroll
        for (int mi = 0; mi < 4; ++mi)
            #pragma unroll
            for (int ni = 0; ni < 4; ++ni)
                acc[mi][ni] = mfma16(af[mi], bfr[ni], acc[mi][ni]);
    }

    // epilogue: C/D layout col = lane&15, row = (lane>>4)*4 + reg
    #pragma unroll
    for (int mi = 0; mi < 4; ++mi) {
        #pragma unroll
        for (int ni = 0; ni < 4; ++ni) {
            #pragma unroll
            for (int j = 0; j < 4; ++j) {
                const int m = m0 + wm * 64 + mi * 16 + lg * 4 + j;
                const int n = n0 + wn * 64 + ni * 16 + l15;
                if constexpr (EPI == 0) {
                    Cout[(size_t)m * N + n] = acc[mi][ni][j];
                } else {
                    const __hip_bfloat16 hv = __float2bfloat16(acc[mi][ni][j]);
                    const int sec = n >> 10;           // 0:q 1:k 2:v
                    const int c   = n & 1023;
                    const int h   = c >> 6, d = c & 63;
                    const int b   = m >> 11, s = m & 2047;
                    const int bh  = b * NH + h;
                    if (sec == 0)      qp [((size_t)bh * SEQ + s) * HD + d] = hv;
                    else if (sec == 1) kp [((size_t)bh * SEQ + s) * HD + d] = hv;
                    else               vtp[((size_t)bh * HD  + d) * SEQ + s] = hv;
                }
            }
        }
    }
}

// ---------------------------------------------------------------------------
// Flash attention (causal). grid = (SEQ/64, NB*NH); 4 waves/block,
// each wave owns 16 q rows, iterates KV tiles of 32.
// ---------------------------------------------------------------------------
__global__ __launch_bounds__(256, 4)
void attn_fwd(const __hip_bfloat16* __restrict__ qp,
              const __hip_bfloat16* __restrict__ kp,
              const __hip_bfloat16* __restrict__ vtp,
              __hip_bfloat16* __restrict__ yp)
{
    __shared__ alignas(16) __hip_bfloat16 P[4][16][32];

    const int tid  = threadIdx.x;
    const int lane = tid & 63, wave = tid >> 6;
    const int l15  = lane & 15, lg = lane >> 4;
    const int qb   = blockIdx.x;
    const int bh   = blockIdx.y;
    const int b    = bh >> 4, h = bh & 15;
    const int q0   = qb * 64 + wave * 16;   // wave's q-row base

    const __hip_bfloat16* Q  = qp  + (size_t)bh * SEQ * HD;
    const __hip_bfloat16* Kp = kp  + (size_t)bh * SEQ * HD;
    const __hip_bfloat16* Vt = vtp + (size_t)bh * HD * SEQ;

    short8 qf[2];
    #pragma unroll
    for (int dk = 0; dk < 2; ++dk)
        qf[dk] = *(const short8*)&Q[(q0 + l15) * HD + dk * 32 + lg * 8];

    f32x4 o[4] = {};
    float m_r[4], l_r[4];
    #pragma unroll
    for (int j = 0; j < 4; ++j) { m_r[j] = -1e30f; l_r[j] = 0.0f; }

    const int ntiles = ((q0 + 15) >> 5) + 1;
    for (int t = 0; t < ntiles; ++t) {
        const int kv0 = t * 32;

        // scores: S = Q K^T  (two 16-col halves)
        f32x4 s0 = {}, s1 = {};
        #pragma unroll
        for (int dk = 0; dk < 2; ++dk) {
            short8 kf0 = *(const short8*)&Kp[(kv0 +      l15) * HD + dk * 32 + lg * 8];
            short8 kf1 = *(const short8*)&Kp[(kv0 + 16 + l15) * HD + dk * 32 + lg * 8];
            s0 = mfma16(qf[dk], kf0, s0);
            s1 = mfma16(qf[dk], kf1, s1);
        }

        // mask + scale + online softmax
        float p0[4], p1[4], mx[4];
        #pragma unroll
        for (int j = 0; j < 4; ++j) {
            const int row = q0 + lg * 4 + j;
            float v0 = (kv0 + l15      <= row) ? s0[j] * 0.125f : -1e30f;
            float v1 = (kv0 + 16 + l15 <= row) ? s1[j] * 0.125f : -1e30f;
            p0[j] = v0; p1[j] = v1;
            mx[j] = fmaxf(v0, v1);
        }
        #pragma unroll
        for (int off = 1; off < 16; off <<= 1) {
            #pragma unroll
            for (int j = 0; j < 4; ++j)
                mx[j] = fmaxf(mx[j], __shfl_xor(mx[j], off));
        }
        float rs[4];
        #pragma unroll
        for (int j = 0; j < 4; ++j) {
            const float mn = fmaxf(m_r[j], mx[j]);
            const float r  = __expf(m_r[j] - mn);
            p0[j] = __expf(p0[j] - mn);
            p1[j] = __expf(p1[j] - mn);
            rs[j] = p0[j] + p1[j];
            m_r[j] = mn;
            l_r[j] *= r;
            #pragma unroll
            for (int dt = 0; dt < 4; ++dt) o[dt][j] *= r;
        }
        #pragma unroll
        for (int off = 1; off < 16; off <<= 1) {
            #pragma unroll
            for (int j = 0; j < 4; ++j)
                rs[j] += __shfl_xor(rs[j], off);
        }
        #pragma unroll
        for (int j = 0; j < 4; ++j) l_r[j] += rs[j];

        // P -> bf16 via wave-private LDS tile (layout fixup for A-fragment)
        #pragma unroll
        for (int j = 0; j < 4; ++j) {
            P[wave][lg * 4 + j][l15]      = __float2bfloat16(p0[j]);
            P[wave][lg * 4 + j][16 + l15] = __float2bfloat16(p1[j]);
        }
        asm volatile("s_waitcnt lgkmcnt(0)" ::: "memory");
        __builtin_amdgcn_sched_barrier(0);
        short8 pa = *(const short8*)&P[wave][l15][lg * 8];

        // O += P V   (B operand from Vt rows: contiguous)
        #pragma unroll
        for (int dt = 0; dt < 4; ++dt) {
            short8 vf = *(const short8*)&Vt[(size_t)(dt * 16 + l15) * SEQ + kv0 + lg * 8];
            o[dt] = mfma16(pa, vf, o[dt]);
        }
    }

    // epilogue: y[b, s, h*64 + d]  (bf16 ws)
    #pragma unroll
    for (int j = 0; j < 4; ++j) {
        const float inv_l = 1.0f / l_r[j];
        const int s = q0 + lg * 4 + j;
        #pragma unroll
        for (int dt = 0; dt < 4; ++dt) {
            const int col = h * 64 + dt * 16 + l15;
            yp[((size_t)(b * SEQ + s)) * CH + col] =
                __float2bfloat16(o[dt][j] * inv_l);
        }
    }
}

// ---------------------------------------------------------------------------
extern "C" void kernel_launch(void* const* d_in, const int* in_sizes, int n_in,
                              void* d_out, int out_size, void* d_ws, size_t ws_size,
                              hipStream_t stream)
{
    const float* x      = (const float*)d_in[0];
    const float* w_qkv  = (const float*)d_in[1];
    const float* w_proj = (const float*)d_in[2];
    float* out = (float*)d_out;

    __hip_bfloat16* ws = (__hip_bfloat16*)d_ws;
    __hip_bfloat16* q_ws  = ws;
    __hip_bfloat16* k_ws  = ws + (size_t)QSZ;
    __hip_bfloat16* vt_ws = ws + (size_t)2 * QSZ;
    __hip_bfloat16* y_ws  = ws + (size_t)3 * QSZ;

    // 1) qkv projection: x[4096,1024] @ w_qkv[3072,1024]^T -> q/k/vt (bf16 ws)
    gemm_bt<1, float, float><<<dim3(MROWS / 128, 3072 / 128), 256, 0, stream>>>(
        x, w_qkv, CH, 3 * CH, nullptr, q_ws, k_ws, vt_ws);

    // 2) causal flash attention -> y[b,s,c] (bf16 ws)
    attn_fwd<<<dim3(SEQ / 64, NB * NH), 256, 0, stream>>>(q_ws, k_ws, vt_ws, y_ws);

    // 3) output projection: y[4096,1024] @ w_proj[1024,1024]^T -> out (fp32)
    gemm_bt<0, __hip_bfloat16, float><<<dim3(MROWS / 128, CH / 128), 256, 0, stream>>>(
        y_ws, w_proj, CH, CH, out, nullptr, nullptr, nullptr);
}

// Round 3
// 203.134 us; speedup vs baseline: 1.5144x; 1.5144x over previous
//
#include <hip/hip_runtime.h>
#include <hip/hip_bf16.h>

typedef short short8 __attribute__((ext_vector_type(8)));
typedef float f32x4 __attribute__((ext_vector_type(4)));

#define NB   2
#define SEQ  2048
#define CH   1024
#define NH   16
#define HD   64
#define MROWS (NB*SEQ)          // 4096
#define QSZ  (NB*NH*SEQ*HD)     // 4194304 elems per tensor

__device__ __forceinline__ f32x4 mfma16(short8 a, short8 b, f32x4 c) {
    return __builtin_amdgcn_mfma_f32_16x16x32_bf16(a, b, c, 0, 0, 0);
}

__device__ __forceinline__ short bf16_of(float f) {
    return __builtin_bit_cast(short, __float2bfloat16(f));
}

// load 8 consecutive elements, yielding bf16 short8
__device__ __forceinline__ short8 load8(const __hip_bfloat16* p) {
    return *reinterpret_cast<const short8*>(p);
}
__device__ __forceinline__ short8 load8(const float* p) {
    f32x4 a = *reinterpret_cast<const f32x4*>(p);
    f32x4 b = *reinterpret_cast<const f32x4*>(p + 4);
    short8 r;
    r[0] = bf16_of(a[0]); r[1] = bf16_of(a[1]);
    r[2] = bf16_of(a[2]); r[3] = bf16_of(a[3]);
    r[4] = bf16_of(b[0]); r[5] = bf16_of(b[1]);
    r[6] = bf16_of(b[2]); r[7] = bf16_of(b[3]);
    return r;
}

// ---------------------------------------------------------------------------
// GEMM  C[m,n] = sum_k A[m,k] * W[n,k]   (A row-major [M,K], W row-major [N,K])
// 128x128 tile, BK=32, 4 waves (2x2), each wave 64x64 out = 4x4 MFMA frags.
// EPI=0: fp32 store to Cout[m*N+n]
// EPI=1: qkv routing -> q[b,h,s,d], k[b,h,s,d], vt[b,h,d,s]  (bf16 ws)
// ---------------------------------------------------------------------------
template<int EPI, typename TA, typename TW>
__global__ __launch_bounds__(256, 2)
void gemm_bt(const TA* __restrict__ A,
             const TW* __restrict__ W,
             int K, int N,
             float* __restrict__ Cout,
             __hip_bfloat16* __restrict__ qp,
             __hip_bfloat16* __restrict__ kp,
             __hip_bfloat16* __restrict__ vtp)
{
    __shared__ alignas(16) __hip_bfloat16 Asm[128 * 32];
    __shared__ alignas(16) __hip_bfloat16 Bsm[128 * 32];

    const int tid  = threadIdx.x;
    const int lane = tid & 63;
    const int wave = tid >> 6;
    const int wm   = wave >> 1, wn = wave & 1;
    const int l15  = lane & 15, lg = lane >> 4;
    const int m0   = blockIdx.x * 128;
    const int n0   = blockIdx.y * 128;

    f32x4 acc[4][4] = {};

    const int c0 = tid, c1 = tid + 256;
    const int r0 = c0 >> 2, kc0 = (c0 & 3) << 3;
    const int r1 = c1 >> 2, kc1 = (c1 & 3) << 3;
    const TA* a0p = A + (size_t)(m0 + r0) * K + kc0;
    const TA* a1p = A + (size_t)(m0 + r1) * K + kc1;
    const TW* b0p = W + (size_t)(n0 + r0) * K + kc0;
    const TW* b1p = W + (size_t)(n0 + r1) * K + kc1;

    for (int k0 = 0; k0 < K; k0 += 32) {
        short8 av0 = load8(a0p + k0);
        short8 av1 = load8(a1p + k0);
        short8 bv0 = load8(b0p + k0);
        short8 bv1 = load8(b1p + k0);
        __syncthreads();
        *(short8*)&Asm[c0 * 8] = av0;
        *(short8*)&Asm[c1 * 8] = av1;
        *(short8*)&Bsm[c0 * 8] = bv0;
        *(short8*)&Bsm[c1 * 8] = bv1;
        __syncthreads();

        short8 af[4], bfr[4];
        #pragma unroll
        for (int mi = 0; mi < 4; ++mi)
            af[mi] = *(const short8*)&Asm[(wm * 64 + mi * 16 + l15) * 32 + lg * 8];
        #pragma unroll
        for (int ni = 0; ni < 4; ++ni)
            bfr[ni] = *(const short8*)&Bsm[(wn * 64 + ni * 16 + l15) * 32 + lg * 8];
        #pragma unroll
        for (int mi = 0; mi < 4; ++mi)
            #pragma unroll
            for (int ni = 0; ni < 4; ++ni)
                acc[mi][ni] = mfma16(af[mi], bfr[ni], acc[mi][ni]);
    }

    #pragma unroll
    for (int mi = 0; mi < 4; ++mi) {
        #pragma unroll
        for (int ni = 0; ni < 4; ++ni) {
            #pragma unroll
            for (int j = 0; j < 4; ++j) {
                const int m = m0 + wm * 64 + mi * 16 + lg * 4 + j;
                const int n = n0 + wn * 64 + ni * 16 + l15;
                if constexpr (EPI == 0) {
                    Cout[(size_t)m * N + n] = acc[mi][ni][j];
                } else {
                    const __hip_bfloat16 hv = __float2bfloat16(acc[mi][ni][j]);
                    const int sec = n >> 10;           // 0:q 1:k 2:v
                    const int c   = n & 1023;
                    const int h   = c >> 6, d = c & 63;
                    const int b   = m >> 11, s = m & 2047;
                    const int bh  = b * NH + h;
                    if (sec == 0)      qp [((size_t)bh * SEQ + s) * HD + d] = hv;
                    else if (sec == 1) kp [((size_t)bh * SEQ + s) * HD + d] = hv;
                    else               vtp[((size_t)bh * HD  + d) * SEQ + s] = hv;
                }
            }
        }
    }
}

// ---------------------------------------------------------------------------
// Flash attention v2 (causal). 512 blocks x 256 thr. Each block: one (b,h),
// two paired q-chunks (p and 31-p) of 64 rows -> perfectly balanced work.
// Wave owns 16 q rows; KV tiles of 64; K reg-double-buffered; V issued at
// tile top (consumed after softmax). XCD-grouped bh for KV L2 locality.
// ---------------------------------------------------------------------------
__global__ __launch_bounds__(256, 2)
void attn_fwd2(const __hip_bfloat16* __restrict__ qp,
               const __hip_bfloat16* __restrict__ kp,
               const __hip_bfloat16* __restrict__ vtp,
               __hip_bfloat16* __restrict__ yp)
{
    __shared__ alignas(16) __hip_bfloat16 P[4][16][64];

    const int tid  = threadIdx.x;
    const int lane = tid & 63, wave = tid >> 6;
    const int l15  = lane & 15, lg = lane >> 4;
    const int id   = blockIdx.x;
    const int xcd  = id & 7, slot = id >> 3;
    const int bh   = xcd * 4 + (slot >> 4);   // 16 blocks of same bh land on one XCD
    const int pair = slot & 15;
    const int b    = bh >> 4, h = bh & 15;

    const __hip_bfloat16* Q  = qp  + (size_t)bh * SEQ * HD;
    const __hip_bfloat16* Kp = kp  + (size_t)bh * SEQ * HD;
    const __hip_bfloat16* Vt = vtp + (size_t)bh * HD * SEQ;

    for (int cc = 0; cc < 2; ++cc) {
        const int c  = cc ? (31 - pair) : pair;   // chunk index 0..31
        const int q0 = c * 64 + wave * 16;

        short8 qf[2];
        #pragma unroll
        for (int dk = 0; dk < 2; ++dk)
            qf[dk] = *(const short8*)&Q[(size_t)(q0 + l15) * HD + dk * 32 + lg * 8];

        f32x4 o[4] = {};
        float m_r[4], l_r[4];
        #pragma unroll
        for (int j = 0; j < 4; ++j) { m_r[j] = -1e30f; l_r[j] = 0.0f; }

        short8 KA[4][2], KB[4][2], VF[4][2];

        auto loadK = [&](short8 (&KF)[4][2], int T) {
            const int kv0 = T * 64;
            #pragma unroll
            for (int kf = 0; kf < 4; ++kf)
                #pragma unroll
                for (int dk = 0; dk < 2; ++dk)
                    KF[kf][dk] = *(const short8*)
                        &Kp[(size_t)(kv0 + kf * 16 + l15) * HD + dk * 32 + lg * 8];
        };
        auto loadV = [&](int T) {
            const int kv0 = T * 64;
            #pragma unroll
            for (int dt = 0; dt < 4; ++dt)
                #pragma unroll
                for (int ks = 0; ks < 2; ++ks)
                    VF[dt][ks] = *(const short8*)
                        &Vt[(size_t)(dt * 16 + l15) * SEQ + kv0 + ks * 32 + lg * 8];
        };

        auto compute = [&](short8 (&KF)[4][2], int t) {
            const int kv0 = t * 64;
            f32x4 s[4] = {};
            #pragma unroll
            for (int kf = 0; kf < 4; ++kf)
                #pragma unroll
                for (int dk = 0; dk < 2; ++dk)
                    s[kf] = mfma16(qf[dk], KF[kf][dk], s[kf]);

            float v[4][4], mx[4];
            const bool diag = (t == c);
            #pragma unroll
            for (int j = 0; j < 4; ++j) {
                const int row = q0 + lg * 4 + j;
                #pragma unroll
                for (int kf = 0; kf < 4; ++kf) {
                    float sv = s[kf][j] * 0.125f;
                    if (diag && (kv0 + kf * 16 + l15 > row)) sv = -1e30f;
                    v[kf][j] = sv;
                }
                mx[j] = fmaxf(fmaxf(v[0][j], v[1][j]), fmaxf(v[2][j], v[3][j]));
            }
            #pragma unroll
            for (int off = 1; off < 16; off <<= 1)
                #pragma unroll
                for (int j = 0; j < 4; ++j)
                    mx[j] = fmaxf(mx[j], __shfl_xor(mx[j], off));

            float rs[4];
            #pragma unroll
            for (int j = 0; j < 4; ++j) {
                const float mn = fmaxf(m_r[j], mx[j]);
                const float r  = __expf(m_r[j] - mn);
                #pragma unroll
                for (int kf = 0; kf < 4; ++kf)
                    v[kf][j] = __expf(v[kf][j] - mn);
                rs[j]  = (v[0][j] + v[1][j]) + (v[2][j] + v[3][j]);
                m_r[j] = mn;
                l_r[j] *= r;
                #pragma unroll
                for (int dt = 0; dt < 4; ++dt) o[dt][j] *= r;
            }
            #pragma unroll
            for (int off = 1; off < 16; off <<= 1)
                #pragma unroll
                for (int j = 0; j < 4; ++j)
                    rs[j] += __shfl_xor(rs[j], off);
            #pragma unroll
            for (int j = 0; j < 4; ++j) l_r[j] += rs[j];

            // P -> bf16 A-fragment via wave-private LDS tile
            #pragma unroll
            for (int j = 0; j < 4; ++j)
                #pragma unroll
                for (int kf = 0; kf < 4; ++kf)
                    P[wave][lg * 4 + j][kf * 16 + l15] = __float2bfloat16(v[kf][j]);
            asm volatile("s_waitcnt lgkmcnt(0)" ::: "memory");
            __builtin_amdgcn_sched_barrier(0);
            short8 pa0 = *(const short8*)&P[wave][l15][lg * 8];
            short8 pa1 = *(const short8*)&P[wave][l15][32 + lg * 8];

            #pragma unroll
            for (int dt = 0; dt < 4; ++dt) {
                o[dt] = mfma16(pa0, VF[dt][0], o[dt]);
                o[dt] = mfma16(pa1, VF[dt][1], o[dt]);
            }
        };

        loadK(KA, 0);
        int t = 0;
        while (true) {
            loadV(t);
            if (t < c) loadK(KB, t + 1);
            compute(KA, t);
            ++t; if (t > c) break;
            loadV(t);
            if (t < c) loadK(KA, t + 1);
            compute(KB, t);
            ++t; if (t > c) break;
        }

        // epilogue: y[b, s, h*64 + d]
        #pragma unroll
        for (int j = 0; j < 4; ++j) {
            const float inv_l = 1.0f / l_r[j];
            const int s = q0 + lg * 4 + j;
            #pragma unroll
            for (int dt = 0; dt < 4; ++dt) {
                yp[((size_t)(b * SEQ + s)) * CH + h * 64 + dt * 16 + l15] =
                    __float2bfloat16(o[dt][j] * inv_l);
            }
        }
    }
}

// ---------------------------------------------------------------------------
extern "C" void kernel_launch(void* const* d_in, const int* in_sizes, int n_in,
                              void* d_out, int out_size, void* d_ws, size_t ws_size,
                              hipStream_t stream)
{
    const float* x      = (const float*)d_in[0];
    const float* w_qkv  = (const float*)d_in[1];
    const float* w_proj = (const float*)d_in[2];
    float* out = (float*)d_out;

    __hip_bfloat16* ws = (__hip_bfloat16*)d_ws;
    __hip_bfloat16* q_ws  = ws;
    __hip_bfloat16* k_ws  = ws + (size_t)QSZ;
    __hip_bfloat16* vt_ws = ws + (size_t)2 * QSZ;
    __hip_bfloat16* y_ws  = ws + (size_t)3 * QSZ;

    // 1) qkv projection: x[4096,1024] @ w_qkv[3072,1024]^T -> q/k/vt (bf16 ws)
    gemm_bt<1, float, float><<<dim3(MROWS / 128, 3072 / 128), 256, 0, stream>>>(
        x, w_qkv, CH, 3 * CH, nullptr, q_ws, k_ws, vt_ws);

    // 2) causal flash attention -> y[b,s,c] (bf16 ws)
    attn_fwd2<<<512, 256, 0, stream>>>(q_ws, k_ws, vt_ws, y_ws);

    // 3) output projection: y[4096,1024] @ w_proj[1024,1024]^T -> out (fp32)
    gemm_bt<0, __hip_bfloat16, float><<<dim3(MROWS / 128, CH / 128), 256, 0, stream>>>(
        y_ws, w_proj, CH, CH, out, nullptr, nullptr, nullptr);
}

// Round 4
// 133.527 us; speedup vs baseline: 2.3038x; 1.5213x over previous
//
#include <hip/hip_runtime.h>
#include <hip/hip_bf16.h>

typedef short short8 __attribute__((ext_vector_type(8)));
typedef float f32x4 __attribute__((ext_vector_type(4)));

#define NB   2
#define SEQ  2048
#define CH   1024
#define NH   16
#define HD   64
#define MROWS (NB*SEQ)          // 4096
#define QSZ  (NB*NH*SEQ*HD)     // 4194304 elems per tensor

__device__ __forceinline__ f32x4 mfma16(short8 a, short8 b, f32x4 c) {
    return __builtin_amdgcn_mfma_f32_16x16x32_bf16(a, b, c, 0, 0, 0);
}

__device__ __forceinline__ short bf16_of(float f) {
    return __builtin_bit_cast(short, __float2bfloat16(f));
}

__device__ __forceinline__ short8 load8(const __hip_bfloat16* p) {
    return *reinterpret_cast<const short8*>(p);
}
__device__ __forceinline__ short8 load8(const float* p) {
    f32x4 a = *reinterpret_cast<const f32x4*>(p);
    f32x4 b = *reinterpret_cast<const f32x4*>(p + 4);
    short8 r;
    r[0] = bf16_of(a[0]); r[1] = bf16_of(a[1]);
    r[2] = bf16_of(a[2]); r[3] = bf16_of(a[3]);
    r[4] = bf16_of(b[0]); r[5] = bf16_of(b[1]);
    r[6] = bf16_of(b[2]); r[7] = bf16_of(b[3]);
    return r;
}

// async global->LDS, 16 bytes per lane (lds dest = wave-uniform base + lane*16)
__device__ __forceinline__ void gload_lds16(const void* g, void* l) {
    __builtin_amdgcn_global_load_lds(
        (const __attribute__((address_space(1))) unsigned int*)g,
        (__attribute__((address_space(3))) unsigned int*)l, 16, 0, 0);
}

// ---------------------------------------------------------------------------
// fp32 -> bf16 elementwise convert (n multiple of 2048*8 handled by exact grid)
// ---------------------------------------------------------------------------
__global__ void cvt_bf16_kernel(const float* __restrict__ src,
                                __hip_bfloat16* __restrict__ dst, int n) {
    int i = (blockIdx.x * blockDim.x + threadIdx.x) * 8;
    if (i >= n) return;
    short8 r = load8(src + i);
    *(short8*)&dst[i] = r;
}

// ---------------------------------------------------------------------------
// GEMM  C[m,n] = sum_k A[m,k] * W[n,k]   (A row-major [M,K], W row-major [N,K])
// 128x128 tile, BK=32, 4 waves (2x2), each wave 64x64 out = 4x4 MFMA frags.
// EPI=0: fp32 store to Cout[m*N+n]
// EPI=1: qkv routing -> q[b,h,s,d], k[b,h,s,d], vt[b,h,d,s]  (bf16 ws)
// ---------------------------------------------------------------------------
template<int EPI, typename TA, typename TW>
__global__ __launch_bounds__(256, 2)
void gemm_bt(const TA* __restrict__ A,
             const TW* __restrict__ W,
             int K, int N,
             float* __restrict__ Cout,
             __hip_bfloat16* __restrict__ qp,
             __hip_bfloat16* __restrict__ kp,
             __hip_bfloat16* __restrict__ vtp)
{
    __shared__ alignas(16) __hip_bfloat16 Asm[128 * 32];
    __shared__ alignas(16) __hip_bfloat16 Bsm[128 * 32];

    const int tid  = threadIdx.x;
    const int lane = tid & 63;
    const int wave = tid >> 6;
    const int wm   = wave >> 1, wn = wave & 1;
    const int l15  = lane & 15, lg = lane >> 4;
    const int m0   = blockIdx.x * 128;
    const int n0   = blockIdx.y * 128;

    f32x4 acc[4][4] = {};

    const int c0 = tid, c1 = tid + 256;
    const int r0 = c0 >> 2, kc0 = (c0 & 3) << 3;
    const int r1 = c1 >> 2, kc1 = (c1 & 3) << 3;
    const TA* a0p = A + (size_t)(m0 + r0) * K + kc0;
    const TA* a1p = A + (size_t)(m0 + r1) * K + kc1;
    const TW* b0p = W + (size_t)(n0 + r0) * K + kc0;
    const TW* b1p = W + (size_t)(n0 + r1) * K + kc1;

    for (int k0 = 0; k0 < K; k0 += 32) {
        short8 av0 = load8(a0p + k0);
        short8 av1 = load8(a1p + k0);
        short8 bv0 = load8(b0p + k0);
        short8 bv1 = load8(b1p + k0);
        __syncthreads();
        *(short8*)&Asm[c0 * 8] = av0;
        *(short8*)&Asm[c1 * 8] = av1;
        *(short8*)&Bsm[c0 * 8] = bv0;
        *(short8*)&Bsm[c1 * 8] = bv1;
        __syncthreads();

        short8 af[4], bfr[4];
        #pragma unroll
        for (int mi = 0; mi < 4; ++mi)
            af[mi] = *(const short8*)&Asm[(wm * 64 + mi * 16 + l15) * 32 + lg * 8];
        #pragma unroll
        for (int ni = 0; ni < 4; ++ni)
            bfr[ni] = *(const short8*)&Bsm[(wn * 64 + ni * 16 + l15) * 32 + lg * 8];
        #pragma unroll
        for (int mi = 0; mi < 4; ++mi)
            #pragma unroll
            for (int ni = 0; ni < 4; ++ni)
                acc[mi][ni] = mfma16(af[mi], bfr[ni], acc[mi][ni]);
    }

    #pragma unroll
    for (int mi = 0; mi < 4; ++mi) {
        #pragma unroll
        for (int ni = 0; ni < 4; ++ni) {
            #pragma unroll
            for (int j = 0; j < 4; ++j) {
                const int m = m0 + wm * 64 + mi * 16 + lg * 4 + j;
                const int n = n0 + wn * 64 + ni * 16 + l15;
                if constexpr (EPI == 0) {
                    Cout[(size_t)m * N + n] = acc[mi][ni][j];
                } else {
                    const __hip_bfloat16 hv = __float2bfloat16(acc[mi][ni][j]);
                    const int sec = n >> 10;           // 0:q 1:k 2:v
                    const int c   = n & 1023;
                    const int h   = c >> 6, d = c & 63;
                    const int b   = m >> 11, s = m & 2047;
                    const int bh  = b * NH + h;
                    if (sec == 0)      qp [((size_t)bh * SEQ + s) * HD + d] = hv;
                    else if (sec == 1) kp [((size_t)bh * SEQ + s) * HD + d] = hv;
                    else               vtp[((size_t)bh * HD  + d) * SEQ + s] = hv;
                }
            }
        }
    }
}

// ---------------------------------------------------------------------------
// Flash attention v3 (causal). 1024 blocks x 256 thr; block = one (bh, chunk)
// of 64 q rows (4 waves x 16 rows). Heavy chunks dispatch first (LPT).
// K/V tiles (64x64 bf16) staged to LDS via global_load_lds, double-buffered,
// one barrier per tile. XOR swizzle applied by pre-swizzling the GLOBAL
// source address (LDS stays linear for the DMA); fragment ds_reads unswizzle.
// Row-sum l accumulated by MFMA against a ones vector (no sum shuffles).
// ---------------------------------------------------------------------------
__global__ __launch_bounds__(256, 2)
void attn_fwd3(const __hip_bfloat16* __restrict__ qp,
               const __hip_bfloat16* __restrict__ kp,
               const __hip_bfloat16* __restrict__ vtp,
               __hip_bfloat16* __restrict__ yp)
{
    __shared__ alignas(16) __hip_bfloat16 Ksm[2][64 * 64];   // 8KB each
    __shared__ alignas(16) __hip_bfloat16 Vsm[2][64 * 64];
    __shared__ alignas(16) __hip_bfloat16 P[4][16][72];      // +pad vs bank conflicts

    const int tid  = threadIdx.x;
    const int lane = tid & 63, wave = tid >> 6;
    const int l15  = lane & 15, lg = lane >> 4;
    const int id   = blockIdx.x;
    const int c    = 31 - (id >> 5);          // chunk; heavy first
    const int bh   = id & 31;
    const int b    = bh >> 4, h = bh & 15;
    const int q0   = c * 64 + wave * 16;

    const __hip_bfloat16* Q  = qp  + (size_t)bh * SEQ * HD;
    const __hip_bfloat16* Kp = kp  + (size_t)bh * SEQ * HD;
    const __hip_bfloat16* Vt = vtp + (size_t)bh * HD * SEQ;

    short8 qf[2];
    #pragma unroll
    for (int dk = 0; dk < 2; ++dk)
        qf[dk] = *(const short8*)&Q[(size_t)(q0 + l15) * HD + dk * 32 + lg * 8];

    const short ONE = 0x3F80;   // bf16 1.0
    short8 ones;
    #pragma unroll
    for (int i = 0; i < 8; ++i) ones[i] = ONE;

    f32x4 o[4] = {};
    f32x4 accl = {};
    float m_r[4];
    #pragma unroll
    for (int j = 0; j < 4; ++j) m_r[j] = -1e30f;

    // stage K/V tile t into buffer `buf` (each thread: 2 K + 2 V chunks)
    auto stage = [&](int buf, int t) {
        const int kv0 = t * 64;
        #pragma unroll
        for (int j = 0; j < 2; ++j) {
            const int ch  = j * 256 + tid;          // 0..511
            const int row = ch >> 3, cb = ch & 7;
            const int cbs = cb ^ (row & 7);         // pre-swizzled source block
            gload_lds16(Kp + (size_t)(kv0 + row) * HD + cbs * 8,
                        &Ksm[buf][(j * 256 + wave * 64) * 8]);
            gload_lds16(Vt + (size_t)row * SEQ + kv0 + cbs * 8,
                        &Vsm[buf][(j * 256 + wave * 64) * 8]);
        }
    };

    auto compute = [&](int buf, int t) {
        const int kv0 = t * 64;
        f32x4 s[4] = {};
        #pragma unroll
        for (int kf = 0; kf < 4; ++kf)
            #pragma unroll
            for (int dk = 0; dk < 2; ++dk) {
                short8 kfrag = *(const short8*)
                    &Ksm[buf][(kf * 16 + l15) * 64 + (((dk * 4 + lg) ^ (l15 & 7)) * 8)];
                s[kf] = mfma16(qf[dk], kfrag, s[kf]);
            }

        float v[4][4], mx[4];
        const bool diag = (t == c);
        #pragma unroll
        for (int j = 0; j < 4; ++j) {
            const int row = q0 + lg * 4 + j;
            #pragma unroll
            for (int kf = 0; kf < 4; ++kf) {
                float sv = s[kf][j] * 0.125f;
                if (diag && (kv0 + kf * 16 + l15 > row)) sv = -1e30f;
                v[kf][j] = sv;
            }
            mx[j] = fmaxf(fmaxf(v[0][j], v[1][j]), fmaxf(v[2][j], v[3][j]));
        }
        #pragma unroll
        for (int off = 1; off < 16; off <<= 1)
            #pragma unroll
            for (int j = 0; j < 4; ++j)
                mx[j] = fmaxf(mx[j], __shfl_xor(mx[j], off));

        #pragma unroll
        for (int j = 0; j < 4; ++j) {
            const float mn = fmaxf(m_r[j], mx[j]);
            const float r  = __expf(m_r[j] - mn);
            #pragma unroll
            for (int kf = 0; kf < 4; ++kf)
                v[kf][j] = __expf(v[kf][j] - mn);
            m_r[j] = mn;
            accl[j] *= r;
            #pragma unroll
            for (int dt = 0; dt < 4; ++dt) o[dt][j] *= r;
        }

        // P -> bf16 A-fragment via wave-private LDS tile
        #pragma unroll
        for (int j = 0; j < 4; ++j)
            #pragma unroll
            for (int kf = 0; kf < 4; ++kf)
                P[wave][lg * 4 + j][kf * 16 + l15] = __float2bfloat16(v[kf][j]);
        asm volatile("s_waitcnt lgkmcnt(0)" ::: "memory");
        __builtin_amdgcn_sched_barrier(0);
        short8 pa0 = *(const short8*)&P[wave][l15][lg * 8];
        short8 pa1 = *(const short8*)&P[wave][l15][32 + lg * 8];

        // row-sum via ones-MFMA (all cols get the row sum)
        accl = mfma16(pa0, ones, accl);
        accl = mfma16(pa1, ones, accl);

        #pragma unroll
        for (int dt = 0; dt < 4; ++dt) {
            short8 vf0 = *(const short8*)
                &Vsm[buf][(dt * 16 + l15) * 64 + (((0 + lg) ^ (l15 & 7)) * 8)];
            short8 vf1 = *(const short8*)
                &Vsm[buf][(dt * 16 + l15) * 64 + (((4 + lg) ^ (l15 & 7)) * 8)];
            o[dt] = mfma16(pa0, vf0, o[dt]);
            o[dt] = mfma16(pa1, vf1, o[dt]);
        }
    };

    stage(0, 0);
    for (int t = 0; t <= c; ++t) {
        const int cur = t & 1;
        __syncthreads();                 // buf[cur] staged (vmcnt drained here)
        if (t < c) stage(cur ^ 1, t + 1);
        compute(cur, t);
    }

    // epilogue: y[b, s, h*64 + d]
    #pragma unroll
    for (int j = 0; j < 4; ++j) {
        const float inv_l = 1.0f / accl[j];
        const int s = q0 + lg * 4 + j;
        #pragma unroll
        for (int dt = 0; dt < 4; ++dt) {
            yp[((size_t)(b * SEQ + s)) * CH + h * 64 + dt * 16 + l15] =
                __float2bfloat16(o[dt][j] * inv_l);
        }
    }
}

// ---------------------------------------------------------------------------
extern "C" void kernel_launch(void* const* d_in, const int* in_sizes, int n_in,
                              void* d_out, int out_size, void* d_ws, size_t ws_size,
                              hipStream_t stream)
{
    const float* x      = (const float*)d_in[0];
    const float* w_qkv  = (const float*)d_in[1];
    const float* w_proj = (const float*)d_in[2];
    float* out = (float*)d_out;

    __hip_bfloat16* ws = (__hip_bfloat16*)d_ws;

    const size_t NX  = (size_t)MROWS * CH;        // 4,194,304
    const size_t NWQ = (size_t)3 * CH * CH;       // 3,145,728
    const size_t NWP = (size_t)CH * CH;           // 1,048,576

    if (ws_size >= 41943040ull) {
        // big path: pre-convert everything to bf16
        __hip_bfloat16* xb   = ws;                     // dies after gemm1
        __hip_bfloat16* wqb  = ws + NX;                // dies after gemm1
        __hip_bfloat16* wpb  = ws + NX + NWQ;
        __hip_bfloat16* q_ws = ws + NX + NWQ + NWP;
        __hip_bfloat16* k_ws = q_ws + (size_t)QSZ;
        __hip_bfloat16* vt_ws= k_ws + (size_t)QSZ;
        __hip_bfloat16* y_ws = xb;                     // reuse xb slot

        cvt_bf16_kernel<<<NX  / 2048, 256, 0, stream>>>(x,      xb,  (int)NX);
        cvt_bf16_kernel<<<NWQ / 2048, 256, 0, stream>>>(w_qkv,  wqb, (int)NWQ);
        cvt_bf16_kernel<<<NWP / 2048, 256, 0, stream>>>(w_proj, wpb, (int)NWP);

        gemm_bt<1, __hip_bfloat16, __hip_bfloat16>
            <<<dim3(MROWS / 128, 3072 / 128), 256, 0, stream>>>(
            xb, wqb, CH, 3 * CH, nullptr, q_ws, k_ws, vt_ws);

        attn_fwd3<<<1024, 256, 0, stream>>>(q_ws, k_ws, vt_ws, y_ws);

        gemm_bt<0, __hip_bfloat16, __hip_bfloat16>
            <<<dim3(MROWS / 128, CH / 128), 256, 0, stream>>>(
            y_ws, wpb, CH, CH, out, nullptr, nullptr, nullptr);
    } else {
        // fallback: fp32 operands converted in the GEMM staging path
        __hip_bfloat16* q_ws  = ws;
        __hip_bfloat16* k_ws  = ws + (size_t)QSZ;
        __hip_bfloat16* vt_ws = ws + (size_t)2 * QSZ;
        __hip_bfloat16* y_ws  = ws + (size_t)3 * QSZ;

        gemm_bt<1, float, float><<<dim3(MROWS / 128, 3072 / 128), 256, 0, stream>>>(
            x, w_qkv, CH, 3 * CH, nullptr, q_ws, k_ws, vt_ws);

        attn_fwd3<<<1024, 256, 0, stream>>>(q_ws, k_ws, vt_ws, y_ws);

        gemm_bt<0, __hip_bfloat16, float><<<dim3(MROWS / 128, CH / 128), 256, 0, stream>>>(
            y_ws, w_proj, CH, CH, out, nullptr, nullptr, nullptr);
    }
}

// Round 5
// 125.737 us; speedup vs baseline: 2.4466x; 1.0620x over previous
//
#include <hip/hip_runtime.h>
#include <hip/hip_bf16.h>

typedef short short8 __attribute__((ext_vector_type(8)));
typedef float f32x4 __attribute__((ext_vector_type(4)));

#define NB   2
#define SEQ  2048
#define CH   1024
#define NH   16
#define HD   64
#define MROWS (NB*SEQ)          // 4096
#define QSZ  (NB*NH*SEQ*HD)     // 4194304 elems per tensor
#define NX   ((size_t)MROWS * CH)        // 4,194,304
#define NWQ  ((size_t)3 * CH * CH)       // 3,145,728
#define NWP  ((size_t)CH * CH)           // 1,048,576

__device__ __forceinline__ f32x4 mfma16(short8 a, short8 b, f32x4 c) {
    return __builtin_amdgcn_mfma_f32_16x16x32_bf16(a, b, c, 0, 0, 0);
}

__device__ __forceinline__ short bf16_of(float f) {
    return __builtin_bit_cast(short, __float2bfloat16(f));
}

__device__ __forceinline__ short8 load8(const __hip_bfloat16* p) {
    return *reinterpret_cast<const short8*>(p);
}
__device__ __forceinline__ short8 load8(const float* p) {
    f32x4 a = *reinterpret_cast<const f32x4*>(p);
    f32x4 b = *reinterpret_cast<const f32x4*>(p + 4);
    short8 r;
    r[0] = bf16_of(a[0]); r[1] = bf16_of(a[1]);
    r[2] = bf16_of(a[2]); r[3] = bf16_of(a[3]);
    r[4] = bf16_of(b[0]); r[5] = bf16_of(b[1]);
    r[6] = bf16_of(b[2]); r[7] = bf16_of(b[3]);
    return r;
}

// async global->LDS, 16 bytes per lane (lds dest = wave-uniform base + lane*16)
__device__ __forceinline__ void gload_lds16(const void* g, void* l) {
    __builtin_amdgcn_global_load_lds(
        (const __attribute__((address_space(1))) unsigned int*)g,
        (__attribute__((address_space(3))) unsigned int*)l, 16, 0, 0);
}

// ---------------------------------------------------------------------------
// fused fp32 -> bf16 convert of x | w_qkv | w_proj into contiguous ws region
// ---------------------------------------------------------------------------
__global__ void cvt3_kernel(const float* __restrict__ x,
                            const float* __restrict__ wq,
                            const float* __restrict__ wp,
                            __hip_bfloat16* __restrict__ dst) {
    const size_t i = ((size_t)blockIdx.x * 256 + threadIdx.x) * 8;
    const float* src;
    size_t off;
    if (i < NX)            { src = x;  off = i; }
    else if (i < NX + NWQ) { src = wq; off = i - NX; }
    else                   { src = wp; off = i - NX - NWQ; }
    *(short8*)&dst[i] = load8(src + off);
}

// ---------------------------------------------------------------------------
// GEMM v2 (m97 structure): C[m,n] = sum_k A[m,k]*W[n,k], bf16 in, 128x128
// tile, BK=32, global_load_lds staging double-buffered, 1 barrier / K-step.
// EPI=0: fp32 store; EPI=1: qkv routing q/k/vt.
// ---------------------------------------------------------------------------
template<int EPI>
__global__ __launch_bounds__(256, 2)
void gemm_bt2(const __hip_bfloat16* __restrict__ A,
              const __hip_bfloat16* __restrict__ W,
              int K, int N,
              float* __restrict__ Cout,
              __hip_bfloat16* __restrict__ qp,
              __hip_bfloat16* __restrict__ kp,
              __hip_bfloat16* __restrict__ vtp)
{
    __shared__ alignas(16) __hip_bfloat16 Asm[2][128 * 32];
    __shared__ alignas(16) __hip_bfloat16 Bsm[2][128 * 32];

    const int tid  = threadIdx.x;
    const int lane = tid & 63;
    const int wave = tid >> 6;
    const int wm   = wave >> 1, wn = wave & 1;
    const int l15  = lane & 15, lg = lane >> 4;
    const int m0   = blockIdx.x * 128;
    const int n0   = blockIdx.y * 128;

    f32x4 acc[4][4] = {};

    // staging geometry: wave w stages rows [w*32, w*32+32) of A and of B.
    // lane l: row-in-group = l>>2, col-chunk = (l&3)*8 elems.
    const int srow = lane >> 2;
    const int scol = (lane & 3) * 8;

    auto stage = [&](int buf, int k0) {
        #pragma unroll
        for (int half = 0; half < 2; ++half) {
            const int row = wave * 32 + half * 16;
            gload_lds16(A + (size_t)(m0 + row + srow) * K + k0 + scol,
                        &Asm[buf][row * 32]);
            gload_lds16(W + (size_t)(n0 + row + srow) * K + k0 + scol,
                        &Bsm[buf][row * 32]);
        }
    };

    auto compute = [&](int buf) {
        short8 af[4], bfr[4];
        #pragma unroll
        for (int mi = 0; mi < 4; ++mi)
            af[mi] = *(const short8*)&Asm[buf][(wm * 64 + mi * 16 + l15) * 32 + lg * 8];
        #pragma unroll
        for (int ni = 0; ni < 4; ++ni)
            bfr[ni] = *(const short8*)&Bsm[buf][(wn * 64 + ni * 16 + l15) * 32 + lg * 8];
        #pragma unroll
        for (int mi = 0; mi < 4; ++mi)
            #pragma unroll
            for (int ni = 0; ni < 4; ++ni)
                acc[mi][ni] = mfma16(af[mi], bfr[ni], acc[mi][ni]);
    };

    stage(0, 0);
    int it = 0;
    for (int k0 = 0; k0 < K; k0 += 32, ++it) {
        const int cur = it & 1;
        __syncthreads();                  // buf[cur] staged (vmcnt drained)
        if (k0 + 32 < K) stage(cur ^ 1, k0 + 32);
        compute(cur);
    }

    #pragma unroll
    for (int mi = 0; mi < 4; ++mi) {
        #pragma unroll
        for (int ni = 0; ni < 4; ++ni) {
            #pragma unroll
            for (int j = 0; j < 4; ++j) {
                const int m = m0 + wm * 64 + mi * 16 + lg * 4 + j;
                const int n = n0 + wn * 64 + ni * 16 + l15;
                if constexpr (EPI == 0) {
                    Cout[(size_t)m * N + n] = acc[mi][ni][j];
                } else {
                    const __hip_bfloat16 hv = __float2bfloat16(acc[mi][ni][j]);
                    const int sec = n >> 10;           // 0:q 1:k 2:v
                    const int c   = n & 1023;
                    const int h   = c >> 6, d = c & 63;
                    const int b   = m >> 11, s = m & 2047;
                    const int bh  = b * NH + h;
                    if (sec == 0)      qp [((size_t)bh * SEQ + s) * HD + d] = hv;
                    else if (sec == 1) kp [((size_t)bh * SEQ + s) * HD + d] = hv;
                    else               vtp[((size_t)bh * HD  + d) * SEQ + s] = hv;
                }
            }
        }
    }
}

// ---------------------------------------------------------------------------
// legacy reg-staged GEMM (fallback path only, fp32-capable operands)
// ---------------------------------------------------------------------------
template<int EPI, typename TA, typename TW>
__global__ __launch_bounds__(256, 2)
void gemm_bt(const TA* __restrict__ A,
             const TW* __restrict__ W,
             int K, int N,
             float* __restrict__ Cout,
             __hip_bfloat16* __restrict__ qp,
             __hip_bfloat16* __restrict__ kp,
             __hip_bfloat16* __restrict__ vtp)
{
    __shared__ alignas(16) __hip_bfloat16 Asm[128 * 32];
    __shared__ alignas(16) __hip_bfloat16 Bsm[128 * 32];

    const int tid  = threadIdx.x;
    const int lane = tid & 63;
    const int wave = tid >> 6;
    const int wm   = wave >> 1, wn = wave & 1;
    const int l15  = lane & 15, lg = lane >> 4;
    const int m0   = blockIdx.x * 128;
    const int n0   = blockIdx.y * 128;

    f32x4 acc[4][4] = {};

    const int c0 = tid, c1 = tid + 256;
    const int r0 = c0 >> 2, kc0 = (c0 & 3) << 3;
    const int r1 = c1 >> 2, kc1 = (c1 & 3) << 3;
    const TA* a0p = A + (size_t)(m0 + r0) * K + kc0;
    const TA* a1p = A + (size_t)(m0 + r1) * K + kc1;
    const TW* b0p = W + (size_t)(n0 + r0) * K + kc0;
    const TW* b1p = W + (size_t)(n0 + r1) * K + kc1;

    for (int k0 = 0; k0 < K; k0 += 32) {
        short8 av0 = load8(a0p + k0);
        short8 av1 = load8(a1p + k0);
        short8 bv0 = load8(b0p + k0);
        short8 bv1 = load8(b1p + k0);
        __syncthreads();
        *(short8*)&Asm[c0 * 8] = av0;
        *(short8*)&Asm[c1 * 8] = av1;
        *(short8*)&Bsm[c0 * 8] = bv0;
        *(short8*)&Bsm[c1 * 8] = bv1;
        __syncthreads();

        short8 af[4], bfr[4];
        #pragma unroll
        for (int mi = 0; mi < 4; ++mi)
            af[mi] = *(const short8*)&Asm[(wm * 64 + mi * 16 + l15) * 32 + lg * 8];
        #pragma unroll
        for (int ni = 0; ni < 4; ++ni)
            bfr[ni] = *(const short8*)&Bsm[(wn * 64 + ni * 16 + l15) * 32 + lg * 8];
        #pragma unroll
        for (int mi = 0; mi < 4; ++mi)
            #pragma unroll
            for (int ni = 0; ni < 4; ++ni)
                acc[mi][ni] = mfma16(af[mi], bfr[ni], acc[mi][ni]);
    }

    #pragma unroll
    for (int mi = 0; mi < 4; ++mi) {
        #pragma unroll
        for (int ni = 0; ni < 4; ++ni) {
            #pragma unroll
            for (int j = 0; j < 4; ++j) {
                const int m = m0 + wm * 64 + mi * 16 + lg * 4 + j;
                const int n = n0 + wn * 64 + ni * 16 + l15;
                if constexpr (EPI == 0) {
                    Cout[(size_t)m * N + n] = acc[mi][ni][j];
                } else {
                    const __hip_bfloat16 hv = __float2bfloat16(acc[mi][ni][j]);
                    const int sec = n >> 10;
                    const int c   = n & 1023;
                    const int h   = c >> 6, d = c & 63;
                    const int b   = m >> 11, s = m & 2047;
                    const int bh  = b * NH + h;
                    if (sec == 0)      qp [((size_t)bh * SEQ + s) * HD + d] = hv;
                    else if (sec == 1) kp [((size_t)bh * SEQ + s) * HD + d] = hv;
                    else               vtp[((size_t)bh * HD  + d) * SEQ + s] = hv;
                }
            }
        }
    }
}

// ---------------------------------------------------------------------------
// Flash attention v3.1 (causal). 1024 blocks x 256 thr; block = (bh, chunk),
// heavy chunks first. K/V 64x64 tiles via global_load_lds, double-buffered,
// pre-swizzled source. Defer-max (T13, THR=8). 3 blocks/CU target.
// ---------------------------------------------------------------------------
__global__ __launch_bounds__(256, 3)
void attn_fwd3(const __hip_bfloat16* __restrict__ qp,
               const __hip_bfloat16* __restrict__ kp,
               const __hip_bfloat16* __restrict__ vtp,
               __hip_bfloat16* __restrict__ yp)
{
    __shared__ alignas(16) __hip_bfloat16 Ksm[2][64 * 64];
    __shared__ alignas(16) __hip_bfloat16 Vsm[2][64 * 64];
    __shared__ alignas(16) __hip_bfloat16 P[4][16][72];

    const int tid  = threadIdx.x;
    const int lane = tid & 63, wave = tid >> 6;
    const int l15  = lane & 15, lg = lane >> 4;
    const int id   = blockIdx.x;
    const int c    = 31 - (id >> 5);          // chunk; heavy first
    const int bh   = id & 31;
    const int b    = bh >> 4, h = bh & 15;
    const int q0   = c * 64 + wave * 16;

    const __hip_bfloat16* Q  = qp  + (size_t)bh * SEQ * HD;
    const __hip_bfloat16* Kp = kp  + (size_t)bh * SEQ * HD;
    const __hip_bfloat16* Vt = vtp + (size_t)bh * HD * SEQ;

    short8 qf[2];
    #pragma unroll
    for (int dk = 0; dk < 2; ++dk)
        qf[dk] = *(const short8*)&Q[(size_t)(q0 + l15) * HD + dk * 32 + lg * 8];

    const short ONE = 0x3F80;   // bf16 1.0
    short8 ones;
    #pragma unroll
    for (int i = 0; i < 8; ++i) ones[i] = ONE;

    f32x4 o[4] = {};
    f32x4 accl = {};
    float m_r[4];
    #pragma unroll
    for (int j = 0; j < 4; ++j) m_r[j] = -1e30f;

    auto stage = [&](int buf, int t) {
        const int kv0 = t * 64;
        #pragma unroll
        for (int j = 0; j < 2; ++j) {
            const int ch  = j * 256 + tid;
            const int row = ch >> 3, cb = ch & 7;
            const int cbs = cb ^ (row & 7);         // pre-swizzled source block
            gload_lds16(Kp + (size_t)(kv0 + row) * HD + cbs * 8,
                        &Ksm[buf][(j * 256 + wave * 64) * 8]);
            gload_lds16(Vt + (size_t)row * SEQ + kv0 + cbs * 8,
                        &Vsm[buf][(j * 256 + wave * 64) * 8]);
        }
    };

    auto compute = [&](int buf, int t) {
        const int kv0 = t * 64;
        f32x4 s[4] = {};
        #pragma unroll
        for (int kf = 0; kf < 4; ++kf)
            #pragma unroll
            for (int dk = 0; dk < 2; ++dk) {
                short8 kfrag = *(const short8*)
                    &Ksm[buf][(kf * 16 + l15) * 64 + (((dk * 4 + lg) ^ (l15 & 7)) * 8)];
                s[kf] = mfma16(qf[dk], kfrag, s[kf]);
            }

        float v[4][4], mx[4];
        const bool diag = (t == c);
        #pragma unroll
        for (int j = 0; j < 4; ++j) {
            const int row = q0 + lg * 4 + j;
            #pragma unroll
            for (int kf = 0; kf < 4; ++kf) {
                float sv = s[kf][j] * 0.125f;
                if (diag && (kv0 + kf * 16 + l15 > row)) sv = -1e30f;
                v[kf][j] = sv;
            }
            mx[j] = fmaxf(fmaxf(v[0][j], v[1][j]), fmaxf(v[2][j], v[3][j]));
        }
        #pragma unroll
        for (int off = 1; off < 16; off <<= 1)
            #pragma unroll
            for (int j = 0; j < 4; ++j)
                mx[j] = fmaxf(mx[j], __shfl_xor(mx[j], off));

        // defer-max (T13): rescale only when tile max exceeds running max + 8
        bool needs = false;
        #pragma unroll
        for (int j = 0; j < 4; ++j) needs |= (mx[j] > m_r[j] + 8.0f);
        if (__any(needs)) {
            #pragma unroll
            for (int j = 0; j < 4; ++j) {
                const float mn = fmaxf(m_r[j], mx[j]);
                const float r  = __expf(m_r[j] - mn);
                m_r[j] = mn;
                accl[j] *= r;
                #pragma unroll
                for (int dt = 0; dt < 4; ++dt) o[dt][j] *= r;
            }
        }
        #pragma unroll
        for (int j = 0; j < 4; ++j)
            #pragma unroll
            for (int kf = 0; kf < 4; ++kf)
                v[kf][j] = __expf(v[kf][j] - m_r[j]);

        // P -> bf16 A-fragment via wave-private LDS tile
        #pragma unroll
        for (int j = 0; j < 4; ++j)
            #pragma unroll
            for (int kf = 0; kf < 4; ++kf)
                P[wave][lg * 4 + j][kf * 16 + l15] = __float2bfloat16(v[kf][j]);
        asm volatile("s_waitcnt lgkmcnt(0)" ::: "memory");
        __builtin_amdgcn_sched_barrier(0);
        short8 pa0 = *(const short8*)&P[wave][l15][lg * 8];
        short8 pa1 = *(const short8*)&P[wave][l15][32 + lg * 8];

        // row-sum via ones-MFMA
        accl = mfma16(pa0, ones, accl);
        accl = mfma16(pa1, ones, accl);

        #pragma unroll
        for (int dt = 0; dt < 4; ++dt) {
            short8 vf0 = *(const short8*)
                &Vsm[buf][(dt * 16 + l15) * 64 + (((0 + lg) ^ (l15 & 7)) * 8)];
            short8 vf1 = *(const short8*)
                &Vsm[buf][(dt * 16 + l15) * 64 + (((4 + lg) ^ (l15 & 7)) * 8)];
            o[dt] = mfma16(pa0, vf0, o[dt]);
            o[dt] = mfma16(pa1, vf1, o[dt]);
        }
    };

    stage(0, 0);
    for (int t = 0; t <= c; ++t) {
        const int cur = t & 1;
        __syncthreads();
        if (t < c) stage(cur ^ 1, t + 1);
        compute(cur, t);
    }

    #pragma unroll
    for (int j = 0; j < 4; ++j) {
        const float inv_l = 1.0f / accl[j];
        const int s = q0 + lg * 4 + j;
        #pragma unroll
        for (int dt = 0; dt < 4; ++dt) {
            yp[((size_t)(b * SEQ + s)) * CH + h * 64 + dt * 16 + l15] =
                __float2bfloat16(o[dt][j] * inv_l);
        }
    }
}

// ---------------------------------------------------------------------------
extern "C" void kernel_launch(void* const* d_in, const int* in_sizes, int n_in,
                              void* d_out, int out_size, void* d_ws, size_t ws_size,
                              hipStream_t stream)
{
    const float* x      = (const float*)d_in[0];
    const float* w_qkv  = (const float*)d_in[1];
    const float* w_proj = (const float*)d_in[2];
    float* out = (float*)d_out;

    __hip_bfloat16* ws = (__hip_bfloat16*)d_ws;

    if (ws_size >= 41943040ull) {
        __hip_bfloat16* xb   = ws;                     // dies after gemm1
        __hip_bfloat16* wqb  = ws + NX;
        __hip_bfloat16* wpb  = ws + NX + NWQ;
        __hip_bfloat16* q_ws = ws + NX + NWQ + NWP;
        __hip_bfloat16* k_ws = q_ws + (size_t)QSZ;
        __hip_bfloat16* vt_ws= k_ws + (size_t)QSZ;
        __hip_bfloat16* y_ws = xb;                     // reuse xb slot

        cvt3_kernel<<<(NX + NWQ + NWP) / 2048, 256, 0, stream>>>(x, w_qkv, w_proj, ws);

        gemm_bt2<1><<<dim3(MROWS / 128, 3072 / 128), 256, 0, stream>>>(
            xb, wqb, CH, 3 * CH, nullptr, q_ws, k_ws, vt_ws);

        attn_fwd3<<<1024, 256, 0, stream>>>(q_ws, k_ws, vt_ws, y_ws);

        gemm_bt2<0><<<dim3(MROWS / 128, CH / 128), 256, 0, stream>>>(
            y_ws, wpb, CH, CH, out, nullptr, nullptr, nullptr);
    } else {
        __hip_bfloat16* q_ws  = ws;
        __hip_bfloat16* k_ws  = ws + (size_t)QSZ;
        __hip_bfloat16* vt_ws = ws + (size_t)2 * QSZ;
        __hip_bfloat16* y_ws  = ws + (size_t)3 * QSZ;

        gemm_bt<1, float, float><<<dim3(MROWS / 128, 3072 / 128), 256, 0, stream>>>(
            x, w_qkv, CH, 3 * CH, nullptr, q_ws, k_ws, vt_ws);

        attn_fwd3<<<1024, 256, 0, stream>>>(q_ws, k_ws, vt_ws, y_ws);

        gemm_bt<0, __hip_bfloat16, float><<<dim3(MROWS / 128, CH / 128), 256, 0, stream>>>(
            y_ws, w_proj, CH, CH, out, nullptr, nullptr, nullptr);
    }
}

// Round 7
// 115.243 us; speedup vs baseline: 2.6693x; 1.0911x over previous
//
#include <hip/hip_runtime.h>
#include <hip/hip_bf16.h>

typedef short short8 __attribute__((ext_vector_type(8)));
typedef float f32x4 __attribute__((ext_vector_type(4)));

#define NB   2
#define SEQ  2048
#define CH   1024
#define NH   16
#define HD   64
#define MROWS (NB*SEQ)          // 4096
#define QSZ  (NB*NH*SEQ*HD)     // 4194304 elems per tensor
#define NX   ((size_t)MROWS * CH)        // 4,194,304
#define NWQ  ((size_t)3 * CH * CH)       // 3,145,728
#define NWP  ((size_t)CH * CH)           // 1,048,576

__device__ __forceinline__ f32x4 mfma16(short8 a, short8 b, f32x4 c) {
    return __builtin_amdgcn_mfma_f32_16x16x32_bf16(a, b, c, 0, 0, 0);
}

__device__ __forceinline__ short bf16_of(float f) {
    return __builtin_bit_cast(short, __float2bfloat16(f));
}
__device__ __forceinline__ unsigned int pkbf(float a, float b) {
    return (unsigned int)(unsigned short)bf16_of(a)
         | ((unsigned int)(unsigned short)bf16_of(b) << 16);
}

__device__ __forceinline__ short8 load8(const __hip_bfloat16* p) {
    return *reinterpret_cast<const short8*>(p);
}
__device__ __forceinline__ short8 load8(const float* p) {
    f32x4 a = *reinterpret_cast<const f32x4*>(p);
    f32x4 b = *reinterpret_cast<const f32x4*>(p + 4);
    short8 r;
    r[0] = bf16_of(a[0]); r[1] = bf16_of(a[1]);
    r[2] = bf16_of(a[2]); r[3] = bf16_of(a[3]);
    r[4] = bf16_of(b[0]); r[5] = bf16_of(b[1]);
    r[6] = bf16_of(b[2]); r[7] = bf16_of(b[3]);
    return r;
}

// async global->LDS, 16 bytes per lane (lds dest = wave-uniform base + lane*16)
__device__ __forceinline__ void gload_lds16(const void* g, void* l) {
    __builtin_amdgcn_global_load_lds(
        (const __attribute__((address_space(1))) unsigned int*)g,
        (__attribute__((address_space(3))) unsigned int*)l, 16, 0, 0);
}

// ---------------------------------------------------------------------------
// fused fp32 -> bf16 convert of x | w_qkv | w_proj into contiguous ws region
// ---------------------------------------------------------------------------
__global__ void cvt3_kernel(const float* __restrict__ x,
                            const float* __restrict__ wq,
                            const float* __restrict__ wp,
                            __hip_bfloat16* __restrict__ dst) {
    const size_t i = ((size_t)blockIdx.x * 256 + threadIdx.x) * 8;
    const float* src;
    size_t off;
    if (i < NX)            { src = x;  off = i; }
    else if (i < NX + NWQ) { src = wq; off = i - NX; }
    else                   { src = wp; off = i - NX - NWQ; }
    *(short8*)&dst[i] = load8(src + off);
}

// ---------------------------------------------------------------------------
// GEMM v2 (m97 structure): C[m,n] = sum_k A[m,k]*W[n,k], bf16 in, 128x128
// tile, BK=32, global_load_lds staging double-buffered, 1 barrier / K-step.
// EPI=0: fp32 store; EPI=1: qkv routing q/k/vt (q pre-scaled by 0.125).
// ---------------------------------------------------------------------------
template<int EPI>
__global__ __launch_bounds__(256, 3)
void gemm_bt2(const __hip_bfloat16* __restrict__ A,
              const __hip_bfloat16* __restrict__ W,
              int K, int N,
              float* __restrict__ Cout,
              __hip_bfloat16* __restrict__ qp,
              __hip_bfloat16* __restrict__ kp,
              __hip_bfloat16* __restrict__ vtp)
{
    __shared__ alignas(16) __hip_bfloat16 Asm[2][128 * 32];
    __shared__ alignas(16) __hip_bfloat16 Bsm[2][128 * 32];

    const int tid  = threadIdx.x;
    const int lane = tid & 63;
    const int wave = tid >> 6;
    const int wm   = wave >> 1, wn = wave & 1;
    const int l15  = lane & 15, lg = lane >> 4;
    const int m0   = blockIdx.x * 128;
    const int n0   = blockIdx.y * 128;

    f32x4 acc[4][4] = {};

    const int srow = lane >> 2;
    const int scol = (lane & 3) * 8;

    auto stage = [&](int buf, int k0) {
        #pragma unroll
        for (int half = 0; half < 2; ++half) {
            const int row = wave * 32 + half * 16;
            gload_lds16(A + (size_t)(m0 + row + srow) * K + k0 + scol,
                        &Asm[buf][row * 32]);
            gload_lds16(W + (size_t)(n0 + row + srow) * K + k0 + scol,
                        &Bsm[buf][row * 32]);
        }
    };

    auto compute = [&](int buf) {
        short8 af[4], bfr[4];
        #pragma unroll
        for (int mi = 0; mi < 4; ++mi)
            af[mi] = *(const short8*)&Asm[buf][(wm * 64 + mi * 16 + l15) * 32 + lg * 8];
        #pragma unroll
        for (int ni = 0; ni < 4; ++ni)
            bfr[ni] = *(const short8*)&Bsm[buf][(wn * 64 + ni * 16 + l15) * 32 + lg * 8];
        #pragma unroll
        for (int mi = 0; mi < 4; ++mi)
            #pragma unroll
            for (int ni = 0; ni < 4; ++ni)
                acc[mi][ni] = mfma16(af[mi], bfr[ni], acc[mi][ni]);
    };

    stage(0, 0);
    int it = 0;
    for (int k0 = 0; k0 < K; k0 += 32, ++it) {
        const int cur = it & 1;
        __syncthreads();
        if (k0 + 32 < K) stage(cur ^ 1, k0 + 32);
        compute(cur);
    }

    #pragma unroll
    for (int mi = 0; mi < 4; ++mi) {
        #pragma unroll
        for (int ni = 0; ni < 4; ++ni) {
            #pragma unroll
            for (int j = 0; j < 4; ++j) {
                const int m = m0 + wm * 64 + mi * 16 + lg * 4 + j;
                const int n = n0 + wn * 64 + ni * 16 + l15;
                if constexpr (EPI == 0) {
                    Cout[(size_t)m * N + n] = acc[mi][ni][j];
                } else {
                    const int sec = n >> 10;           // 0:q 1:k 2:v
                    const int c   = n & 1023;
                    const int h   = c >> 6, d = c & 63;
                    const int b   = m >> 11, s = m & 2047;
                    const int bh  = b * NH + h;
                    if (sec == 0) {
                        // fold softmax scale 1/sqrt(64) into Q (exact pow2)
                        qp[((size_t)bh * SEQ + s) * HD + d] =
                            __float2bfloat16(acc[mi][ni][j] * 0.125f);
                    } else if (sec == 1) {
                        kp[((size_t)bh * SEQ + s) * HD + d] =
                            __float2bfloat16(acc[mi][ni][j]);
                    } else {
                        vtp[((size_t)bh * HD + d) * SEQ + s] =
                            __float2bfloat16(acc[mi][ni][j]);
                    }
                }
            }
        }
    }
}

// ---------------------------------------------------------------------------
// legacy reg-staged GEMM (fallback path only, fp32-capable operands)
// ---------------------------------------------------------------------------
template<int EPI, typename TA, typename TW>
__global__ __launch_bounds__(256, 2)
void gemm_bt(const TA* __restrict__ A,
             const TW* __restrict__ W,
             int K, int N,
             float* __restrict__ Cout,
             __hip_bfloat16* __restrict__ qp,
             __hip_bfloat16* __restrict__ kp,
             __hip_bfloat16* __restrict__ vtp)
{
    __shared__ alignas(16) __hip_bfloat16 Asm[128 * 32];
    __shared__ alignas(16) __hip_bfloat16 Bsm[128 * 32];

    const int tid  = threadIdx.x;
    const int lane = tid & 63;
    const int wave = tid >> 6;
    const int wm   = wave >> 1, wn = wave & 1;
    const int l15  = lane & 15, lg = lane >> 4;
    const int m0   = blockIdx.x * 128;
    const int n0   = blockIdx.y * 128;

    f32x4 acc[4][4] = {};

    const int c0 = tid, c1 = tid + 256;
    const int r0 = c0 >> 2, kc0 = (c0 & 3) << 3;
    const int r1 = c1 >> 2, kc1 = (c1 & 3) << 3;
    const TA* a0p = A + (size_t)(m0 + r0) * K + kc0;
    const TA* a1p = A + (size_t)(m0 + r1) * K + kc1;
    const TW* b0p = W + (size_t)(n0 + r0) * K + kc0;
    const TW* b1p = W + (size_t)(n0 + r1) * K + kc1;

    for (int k0 = 0; k0 < K; k0 += 32) {
        short8 av0 = load8(a0p + k0);
        short8 av1 = load8(a1p + k0);
        short8 bv0 = load8(b0p + k0);
        short8 bv1 = load8(b1p + k0);
        __syncthreads();
        *(short8*)&Asm[c0 * 8] = av0;
        *(short8*)&Asm[c1 * 8] = av1;
        *(short8*)&Bsm[c0 * 8] = bv0;
        *(short8*)&Bsm[c1 * 8] = bv1;
        __syncthreads();

        short8 af[4], bfr[4];
        #pragma unroll
        for (int mi = 0; mi < 4; ++mi)
            af[mi] = *(const short8*)&Asm[(wm * 64 + mi * 16 + l15) * 32 + lg * 8];
        #pragma unroll
        for (int ni = 0; ni < 4; ++ni)
            bfr[ni] = *(const short8*)&Bsm[(wn * 64 + ni * 16 + l15) * 32 + lg * 8];
        #pragma unroll
        for (int mi = 0; mi < 4; ++mi)
            #pragma unroll
            for (int ni = 0; ni < 4; ++ni)
                acc[mi][ni] = mfma16(af[mi], bfr[ni], acc[mi][ni]);
    }

    #pragma unroll
    for (int mi = 0; mi < 4; ++mi) {
        #pragma unroll
        for (int ni = 0; ni < 4; ++ni) {
            #pragma unroll
            for (int j = 0; j < 4; ++j) {
                const int m = m0 + wm * 64 + mi * 16 + lg * 4 + j;
                const int n = n0 + wn * 64 + ni * 16 + l15;
                if constexpr (EPI == 0) {
                    Cout[(size_t)m * N + n] = acc[mi][ni][j];
                } else {
                    const int sec = n >> 10;
                    const int c   = n & 1023;
                    const int h   = c >> 6, d = c & 63;
                    const int b   = m >> 11, s = m & 2047;
                    const int bh  = b * NH + h;
                    if (sec == 0) {
                        qp[((size_t)bh * SEQ + s) * HD + d] =
                            __float2bfloat16(acc[mi][ni][j] * 0.125f);
                    } else if (sec == 1) {
                        kp[((size_t)bh * SEQ + s) * HD + d] =
                            __float2bfloat16(acc[mi][ni][j]);
                    } else {
                        vtp[((size_t)bh * HD + d) * SEQ + s] =
                            __float2bfloat16(acc[mi][ni][j]);
                    }
                }
            }
        }
    }
}

// ---------------------------------------------------------------------------
// Flash attention v5 (causal). 1024 blocks x 256 thr; block = (bh, chunk),
// heavy chunks first. K/V 64x64 tiles via global_load_lds, double-buffered,
// pre-swizzled source. Swapped QK^T: S^T = mfma(K,Q) -> lane owns q-row l15
// (in-lane row max + 2 shfl_xor; scalar m_r; defer-max T13). P goes through
// a wave-private LDS tile as 8 packed ds_write_b32 (word col = kf*8+lg*2+jp,
// row stride 36 words) and is read back as 2 ds_read_b128 A-fragments
// (word w = lg*4+i covers cols lg*8+2i, lg*8+2i+1). Row-sum via ones-MFMA.
// ---------------------------------------------------------------------------
__global__ __launch_bounds__(256, 3)
void attn_fwd5(const __hip_bfloat16* __restrict__ qp,
               const __hip_bfloat16* __restrict__ kp,
               const __hip_bfloat16* __restrict__ vtp,
               __hip_bfloat16* __restrict__ yp)
{
    __shared__ alignas(16) __hip_bfloat16 Ksm[2][64 * 64];
    __shared__ alignas(16) __hip_bfloat16 Vsm[2][64 * 64];
    __shared__ alignas(16) unsigned int Pw[4][16 * 36];   // packed bf16x2 words

    const int tid  = threadIdx.x;
    const int lane = tid & 63, wave = tid >> 6;
    const int l15  = lane & 15, lg = lane >> 4;
    const int id   = blockIdx.x;
    const int c    = 31 - (id >> 5);          // chunk; heavy first
    const int bh   = id & 31;
    const int b    = bh >> 4, h = bh & 15;
    const int q0   = c * 64 + wave * 16;

    const __hip_bfloat16* Q  = qp  + (size_t)bh * SEQ * HD;
    const __hip_bfloat16* Kp = kp  + (size_t)bh * SEQ * HD;
    const __hip_bfloat16* Vt = vtp + (size_t)bh * HD * SEQ;

    short8 qf[2];
    #pragma unroll
    for (int dk = 0; dk < 2; ++dk)
        qf[dk] = *(const short8*)&Q[(size_t)(q0 + l15) * HD + dk * 32 + lg * 8];

    const short ONE = 0x3F80;   // bf16 1.0
    short8 ones;
    #pragma unroll
    for (int i = 0; i < 8; ++i) ones[i] = ONE;

    f32x4 o[4] = {};
    f32x4 accl = {};
    float m_r = -1e30f;          // running max of q-row l15 (per-lane)

    auto stage = [&](int buf, int t) {
        const int kv0 = t * 64;
        #pragma unroll
        for (int j = 0; j < 2; ++j) {
            const int ch  = j * 256 + tid;
            const int row = ch >> 3, cb = ch & 7;
            const int cbs = cb ^ (row & 7);         // pre-swizzled source block
            gload_lds16(Kp + (size_t)(kv0 + row) * HD + cbs * 8,
                        &Ksm[buf][(j * 256 + wave * 64) * 8]);
            gload_lds16(Vt + (size_t)row * SEQ + kv0 + cbs * 8,
                        &Vsm[buf][(j * 256 + wave * 64) * 8]);
        }
    };

    auto compute = [&](int buf, int t) {
        const int kv0 = t * 64;
        // S^T = K Q^T : C col(l15) = q-row, C row(lg*4+j) = k-col
        f32x4 s[4] = {};
        #pragma unroll
        for (int kf = 0; kf < 4; ++kf)
            #pragma unroll
            for (int dk = 0; dk < 2; ++dk) {
                short8 kfrag = *(const short8*)
                    &Ksm[buf][(kf * 16 + l15) * 64 + (((dk * 4 + lg) ^ (l15 & 7)) * 8)];
                s[kf] = mfma16(kfrag, qf[dk], s[kf]);
            }

        // mask (diag tile only) + in-lane row max
        float v[4][4];
        const bool diag = (t == c);
        const int qrow = q0 + l15;
        #pragma unroll
        for (int kf = 0; kf < 4; ++kf)
            #pragma unroll
            for (int j = 0; j < 4; ++j) {
                float sv = s[kf][j];
                if (diag && (kv0 + kf * 16 + lg * 4 + j > qrow)) sv = -1e30f;
                v[kf][j] = sv;
            }
        float mxv = v[0][0];
        #pragma unroll
        for (int kf = 0; kf < 4; ++kf)
            #pragma unroll
            for (int j = 0; j < 4; ++j)
                mxv = fmaxf(mxv, v[kf][j]);
        mxv = fmaxf(mxv, __shfl_xor(mxv, 16));
        mxv = fmaxf(mxv, __shfl_xor(mxv, 32));   // row max over 64-k tile

        // defer-max (T13): rescale only when tile max exceeds running max + 8
        if (__any(mxv > m_r + 8.0f)) {
            const float mn = fmaxf(m_r, mxv);
            const float r  = __expf(m_r - mn);
            m_r = mn;
            // redistribute r from q-row owner lane (lanes 0..15) to O-layout rows
            float rj[4];
            #pragma unroll
            for (int j = 0; j < 4; ++j)
                rj[j] = __shfl(r, lg * 4 + j);
            #pragma unroll
            for (int j = 0; j < 4; ++j) {
                accl[j] *= rj[j];
                #pragma unroll
                for (int dt = 0; dt < 4; ++dt) o[dt][j] *= rj[j];
            }
        }

        // exp in-lane
        #pragma unroll
        for (int kf = 0; kf < 4; ++kf)
            #pragma unroll
            for (int j = 0; j < 4; ++j)
                v[kf][j] = __expf(v[kf][j] - m_r);

        // pack to bf16x2 words, bounce through wave-private LDS tile.
        // write: row l15, word col = kf*8 + lg*2 + jp  (cols kf*16+lg*4+2jp..+1)
        unsigned int* myP = &Pw[wave][0];
        const int pb = l15 * 36 + lg * 2;
        #pragma unroll
        for (int kf = 0; kf < 4; ++kf) {
            myP[pb + kf * 8]     = pkbf(v[kf][0], v[kf][1]);
            myP[pb + kf * 8 + 1] = pkbf(v[kf][2], v[kf][3]);
        }
        asm volatile("s_waitcnt lgkmcnt(0)" ::: "memory");
        __builtin_amdgcn_sched_barrier(0);
        // read: A-fragment words w = lg*4+i -> cols lg*8+0..7 (pa0), +32 (pa1)
        short8 pa0 = *(const short8*)&Pw[wave][l15 * 36 + lg * 4];
        short8 pa1 = *(const short8*)&Pw[wave][l15 * 36 + 16 + lg * 4];

        // row-sum via ones-MFMA (lands in O-layout)
        accl = mfma16(pa0, ones, accl);
        accl = mfma16(pa1, ones, accl);

        #pragma unroll
        for (int dt = 0; dt < 4; ++dt) {
            short8 vf0 = *(const short8*)
                &Vsm[buf][(dt * 16 + l15) * 64 + (((0 + lg) ^ (l15 & 7)) * 8)];
            short8 vf1 = *(const short8*)
                &Vsm[buf][(dt * 16 + l15) * 64 + (((4 + lg) ^ (l15 & 7)) * 8)];
            o[dt] = mfma16(pa0, vf0, o[dt]);
            o[dt] = mfma16(pa1, vf1, o[dt]);
        }
    };

    stage(0, 0);
    for (int t = 0; t <= c; ++t) {
        const int cur = t & 1;
        __syncthreads();
        if (t < c) stage(cur ^ 1, t + 1);
        compute(cur, t);
    }

    // epilogue: y[b, s, h*64 + d]; O C-layout: row(lg*4+j)=q-row, col(l15)=d
    #pragma unroll
    for (int j = 0; j < 4; ++j) {
        const float inv_l = 1.0f / accl[j];
        const int s = q0 + lg * 4 + j;
        #pragma unroll
        for (int dt = 0; dt < 4; ++dt) {
            yp[((size_t)(b * SEQ + s)) * CH + h * 64 + dt * 16 + l15] =
                __float2bfloat16(o[dt][j] * inv_l);
        }
    }
}

// ---------------------------------------------------------------------------
extern "C" void kernel_launch(void* const* d_in, const int* in_sizes, int n_in,
                              void* d_out, int out_size, void* d_ws, size_t ws_size,
                              hipStream_t stream)
{
    const float* x      = (const float*)d_in[0];
    const float* w_qkv  = (const float*)d_in[1];
    const float* w_proj = (const float*)d_in[2];
    float* out = (float*)d_out;

    __hip_bfloat16* ws = (__hip_bfloat16*)d_ws;

    if (ws_size >= 41943040ull) {
        __hip_bfloat16* xb   = ws;                     // dies after gemm1
        __hip_bfloat16* wqb  = ws + NX;
        __hip_bfloat16* wpb  = ws + NX + NWQ;
        __hip_bfloat16* q_ws = ws + NX + NWQ + NWP;
        __hip_bfloat16* k_ws = q_ws + (size_t)QSZ;
        __hip_bfloat16* vt_ws= k_ws + (size_t)QSZ;
        __hip_bfloat16* y_ws = xb;                     // reuse xb slot

        cvt3_kernel<<<(NX + NWQ + NWP) / 2048, 256, 0, stream>>>(x, w_qkv, w_proj, ws);

        gemm_bt2<1><<<dim3(MROWS / 128, 3072 / 128), 256, 0, stream>>>(
            xb, wqb, CH, 3 * CH, nullptr, q_ws, k_ws, vt_ws);

        attn_fwd5<<<1024, 256, 0, stream>>>(q_ws, k_ws, vt_ws, y_ws);

        gemm_bt2<0><<<dim3(MROWS / 128, CH / 128), 256, 0, stream>>>(
            y_ws, wpb, CH, CH, out, nullptr, nullptr, nullptr);
    } else {
        __hip_bfloat16* q_ws  = ws;
        __hip_bfloat16* k_ws  = ws + (size_t)QSZ;
        __hip_bfloat16* vt_ws = ws + (size_t)2 * QSZ;
        __hip_bfloat16* y_ws  = ws + (size_t)3 * QSZ;

        gemm_bt<1, float, float><<<dim3(MROWS / 128, 3072 / 128), 256, 0, stream>>>(
            x, w_qkv, CH, 3 * CH, nullptr, q_ws, k_ws, vt_ws);

        attn_fwd5<<<1024, 256, 0, stream>>>(q_ws, k_ws, vt_ws, y_ws);

        gemm_bt<0, __hip_bfloat16, float><<<dim3(MROWS / 128, CH / 128), 256, 0, stream>>>(
            y_ws, w_proj, CH, CH, out, nullptr, nullptr, nullptr);
    }
}